// Round 6
// baseline (6608.863 us; speedup 1.0000x reference)
//
#include <hip/hip_runtime.h>
#include <hip/hip_bf16.h>
#include <stdint.h>

#define S_LEN 512
#define BATCH 64
#define DDIM  512
#define HID   512
#define SB    32768   // S_LEN*BATCH

typedef __attribute__((ext_vector_type(8))) short bf16x8;
typedef __attribute__((ext_vector_type(4))) float f32x4;

__device__ __forceinline__ float bf2f(short s) {
  return __uint_as_float(((unsigned)(unsigned short)s) << 16);
}

__device__ __forceinline__ void gload_lds16(const void* g, void* l) {
  __builtin_amdgcn_global_load_lds(
      (const __attribute__((address_space(1))) void*)g,
      (__attribute__((address_space(3))) void*)l, 16, 0, 0);
}

// ---------- prep kernels ----------

__global__ void k_f32_to_bf16(const float* __restrict__ src,
                              __hip_bfloat16* __restrict__ dst, int n) {
  int i = (blockIdx.x * blockDim.x + threadIdx.x) * 8;
  if (i >= n) return;
  float4 a = *(const float4*)(src + i);
  float4 b = *(const float4*)(src + i + 4);
  __hip_bfloat16 t[8];
  t[0] = __float2bfloat16(a.x); t[1] = __float2bfloat16(a.y);
  t[2] = __float2bfloat16(a.z); t[3] = __float2bfloat16(a.w);
  t[4] = __float2bfloat16(b.x); t[5] = __float2bfloat16(b.y);
  t[6] = __float2bfloat16(b.z); t[7] = __float2bfloat16(b.w);
  *(bf16x8*)(dst + i) = *(bf16x8*)t;
}

__global__ void k_permW(const float* __restrict__ src,
                        __hip_bfloat16* __restrict__ dst, int K) {
  int idx = blockIdx.x * 256 + threadIdx.x;
  int p = idx / K, k = idx - p * K;
  int g = p & 3, j = p >> 2;
  dst[idx] = __float2bfloat16(src[(size_t)(g * HID + j) * K + k]);
}

__global__ void k_permB(const float* __restrict__ bih, const float* __restrict__ bhh,
                        float* __restrict__ dst) {
  int p = blockIdx.x * 256 + threadIdx.x;
  int g = p & 3, j = p >> 2;
  dst[p] = bih[g * HID + j] + bhh[g * HID + j];
}

// ---------- input-projection GEMM (unchanged, proven) ----------
__global__ __launch_bounds__(256) void k_gemm_in(
    const __hip_bfloat16* __restrict__ A,
    const __hip_bfloat16* __restrict__ W,
    const float* __restrict__ bsumL,
    __hip_bfloat16* __restrict__ G,
    int K) {
  __shared__ uint4 lds4[2048];
  char* ldsA = (char*)lds4;
  char* ldsB = (char*)lds4 + 16384;
  int tid = threadIdx.x, lane = tid & 63, wid = tid >> 6;
  int wm = wid >> 1, wn = wid & 1;
  int bm = blockIdx.x, by = blockIdx.y;
  int lr = lane & 15, lk = lane >> 4;
  f32x4 acc[4][4] = {};
  const char* gA = (const char*)A;
  const char* gW = (const char*)W;
  for (int kk = 0; kk < K; kk += 64) {
    #pragma unroll
    for (int i = 0; i < 4; i++) {
      int ch = i * 256 + tid;
      int row = ch >> 3, c16 = ch & 7;
      gload_lds16(gA + (size_t)(bm * 128 + row) * (K * 2) + kk * 2 + c16 * 16,
                  ldsA + (i * 256 + wid * 64) * 16);
      gload_lds16(gW + (size_t)(by * 128 + row) * (K * 2) + kk * 2 + c16 * 16,
                  ldsB + (i * 256 + wid * 64) * 16);
    }
    __syncthreads();
    #pragma unroll
    for (int ks = 0; ks < 2; ks++) {
      bf16x8 af[4], bfr[4];
      #pragma unroll
      for (int mi = 0; mi < 4; mi++) {
        int r = wm * 64 + mi * 16 + lr;
        af[mi] = *(const bf16x8*)(ldsA + r * 128 + ks * 64 + lk * 16);
      }
      #pragma unroll
      for (int ni = 0; ni < 4; ni++) {
        int r = wn * 64 + ni * 16 + lr;
        bfr[ni] = *(const bf16x8*)(ldsB + r * 128 + ks * 64 + lk * 16);
      }
      #pragma unroll
      for (int mi = 0; mi < 4; mi++)
        #pragma unroll
        for (int ni = 0; ni < 4; ni++)
          acc[mi][ni] = __builtin_amdgcn_mfma_f32_16x16x32_bf16(
              af[mi], bfr[ni], acc[mi][ni], 0, 0, 0);
    }
    __syncthreads();
  }
  #pragma unroll
  for (int ni = 0; ni < 4; ni++) {
    int n = by * 128 + wn * 64 + ni * 16 + lr;
    int d = n >> 11, p = n & 2047;
    float bias = bsumL[d * 2048 + p];
    #pragma unroll
    for (int mi = 0; mi < 4; mi++) {
      int mbase = bm * 128 + wm * 64 + mi * 16 + lk * 4;
      #pragma unroll
      for (int r = 0; r < 4; r++) {
        int m = mbase + r;
        G[((size_t)d * SB + m) * 2048 + p] =
            __float2bfloat16(acc[mi][ni][r] + bias);
      }
    }
  }
}

// ---------- persistent scan: 256 independent single-wave blocks ----------
// bid -> (wm 0..3 batch-tile, bn 0..31 unit-tile, dir 0..1). Each wave owns
// batches wm*16..+16 x units bn*16..+16: holds Whh slice (256 VGPR) + A-tile
// (64 VGPR) + c-state in regs; gates transposed via wave-private LDS; h
// exchanged by sentinel-validated relaxed agent-scope loads. NO barriers of
// any kind -- each wave advances as soon as its 32 producers (same wm, same
// dir) have published. Loads for step s+1 issue right after publishing h(s).
__global__ __launch_bounds__(64, 1) void k_scan(
    const __hip_bfloat16* __restrict__ G,    // [2][SB][2048]
    const __hip_bfloat16* __restrict__ Whp,  // [2][2048][512] this layer
    __hip_bfloat16* __restrict__ Y,          // [SB][1024], sentinel-filled
    const float* __restrict__ mask,          // [S][B]
    float* __restrict__ outH,                // f32 h out (layer1) or null
    float* __restrict__ hn, float* __restrict__ cn) {
  __shared__ float gatesF[16 * 68];          // wave-private, 4.25KB
  int lane = threadIdx.x;
  int bid = blockIdx.x;
  int wm  = bid & 3;
  int bn  = (bid >> 2) & 31;
  int dir = bid >> 7;
  int lr = lane & 15, lk = lane >> 4;
  const char* Gd = (const char*)G + (size_t)dir * SB * 4096;
  const char* Yb = (const char*)Y;

  // cell mapping: batch cb, 4 local units cu0..cu0+3
  int cb  = wm * 16 + (lane >> 2);
  int cu0 = (lane & 3) * 4;

  // Whh B-fragments: 64 gate-cols x K=512 (256 VGPR)
  bf16x8 bfrag[16][4];
  {
    const char* w0 = (const char*)Whp + (size_t)(dir * 2048 + bn * 64) * 1024;
    #pragma unroll
    for (int ni = 0; ni < 4; ni++)
      #pragma unroll
      for (int ks = 0; ks < 16; ks++)
        bfrag[ks][ni] = *(const bf16x8*)(w0 + (size_t)(ni * 16 + lr) * 1024 +
                                         ks * 64 + lk * 16);
  }

  float creg[4] = {0.f, 0.f, 0.f, 0.f};
  uint64_t A2[32];   // A-tile: 16 slices x 16B (as 2x8B for atomic loads)

  int t0 = dir ? (S_LEN - 1) : 0;
  bf16x8 gvA = *(const bf16x8*)(Gd + (size_t)(t0 * 64 + cb) * 4096 +
                                bn * 128 + (lane & 3) * 32);
  bf16x8 gvB = *(const bf16x8*)(Gd + (size_t)(t0 * 64 + cb) * 4096 +
                                bn * 128 + (lane & 3) * 32 + 16);
  float mreg = mask[t0 * 64 + cb];

  for (int s = 0; s < S_LEN; ++s) {
    int t = dir ? (S_LEN - 1 - s) : s;

    if (s > 0) {
      // A2 loads were issued at the end of the previous iteration.
      // Sentinel-validate; wave-uniform retry rounds.
      int tprev = dir ? t + 1 : t - 1;
      const char* srcH = Yb + (size_t)(tprev * 64 + wm * 16 + lr) * 2048 +
                         dir * 1024 + lk * 16;
      int guard = 0;
      for (;;) {
        int bad = 0;
        #pragma unroll
        for (int i = 0; i < 32; ++i) {
          uint64_t v = A2[i];
          bad |= ((v & 0xFFFFull) == 0xFFFFull);
          bad |= (((v >> 32) & 0xFFFFull) == 0xFFFFull);
        }
        if (!__any(bad)) break;
        __builtin_amdgcn_s_sleep(1);
        if (++guard > (1 << 13)) break;  // hang-proof bail
        #pragma unroll
        for (int i = 0; i < 16; ++i) {
          A2[2 * i] = __hip_atomic_load((const uint64_t*)(srcH + i * 64),
                                        __ATOMIC_RELAXED, __HIP_MEMORY_SCOPE_AGENT);
          A2[2 * i + 1] = __hip_atomic_load((const uint64_t*)(srcH + i * 64 + 8),
                                            __ATOMIC_RELAXED, __HIP_MEMORY_SCOPE_AGENT);
        }
      }
      // MFMA: gates += h_prev @ Whh_slice^T
      f32x4 acc[4] = {};
      #pragma unroll
      for (int ks = 0; ks < 16; ++ks) {
        union { uint64_t u[2]; bf16x8 v; } cvt;
        cvt.u[0] = A2[2 * ks]; cvt.u[1] = A2[2 * ks + 1];
        #pragma unroll
        for (int ni = 0; ni < 4; ++ni)
          acc[ni] = __builtin_amdgcn_mfma_f32_16x16x32_bf16(
              cvt.v, bfrag[ks][ni], acc[ni], 0, 0, 0);
      }
      // wave-local transpose via LDS (no barrier: same-wave RAW handled by
      // lgkmcnt the compiler inserts)
      #pragma unroll
      for (int ni = 0; ni < 4; ++ni)
        #pragma unroll
        for (int r = 0; r < 4; ++r)
          gatesF[((lane >> 4) * 4 + r) * 68 + ni * 16 + lr] = acc[ni][r];
    }

    // cell update: 4 adjacent units (batch cb, units bn*16+cu0..+3)
    float h2v[4], c2v[4];
    #pragma unroll
    for (int j = 0; j < 4; ++j) {
      float gi = 0.f, gf = 0.f, gg = 0.f, go = 0.f;
      if (s > 0) {
        int base = (lane >> 2) * 68 + (lane & 3) * 16 + j * 4;
        gi = gatesF[base + 0]; gf = gatesF[base + 1];
        gg = gatesF[base + 2]; go = gatesF[base + 3];
      }
      const bf16x8& gsel = (j < 2) ? gvA : gvB;
      int e = (j & 1) * 4;
      gi += bf2f(gsel[e + 0]); gf += bf2f(gsel[e + 1]);
      gg += bf2f(gsel[e + 2]); go += bf2f(gsel[e + 3]);
      float si = 1.f / (1.f + __expf(-gi));
      float sf = 1.f / (1.f + __expf(-gf));
      float so = 1.f / (1.f + __expf(-go));
      float tg = 1.f - 2.f / (1.f + __expf(2.f * gg));
      float c2 = sf * creg[j] + si * tg;
      float h2 = so * (1.f - 2.f / (1.f + __expf(2.f * c2)));
      h2 *= mreg; c2 *= mreg;
      creg[j] = c2; h2v[j] = h2; c2v[j] = c2;
    }
    // publish: 4 bf16 packed into one 8B agent-scope store
    {
      __hip_bfloat16 b0 = __float2bfloat16(h2v[0]);
      __hip_bfloat16 b1 = __float2bfloat16(h2v[1]);
      __hip_bfloat16 b2 = __float2bfloat16(h2v[2]);
      __hip_bfloat16 b3 = __float2bfloat16(h2v[3]);
      uint64_t w = (uint64_t)*(unsigned short*)&b0 |
                   ((uint64_t)*(unsigned short*)&b1 << 16) |
                   ((uint64_t)*(unsigned short*)&b2 << 32) |
                   ((uint64_t)*(unsigned short*)&b3 << 48);
      uint64_t* yw = (uint64_t*)((char*)Y + (size_t)(t * 64 + cb) * 2048 +
                                 dir * 1024 + (bn * 16 + cu0) * 2);
      __hip_atomic_store(yw, w, __ATOMIC_RELAXED, __HIP_MEMORY_SCOPE_AGENT);
    }

    if (s < S_LEN - 1) {
      // issue next step's A-loads NOW (poll happens next iteration)
      asm volatile("" ::: "memory");  // keep publish ahead of loads
      const char* srcH = Yb + (size_t)(t * 64 + wm * 16 + lr) * 2048 +
                         dir * 1024 + lk * 16;
      #pragma unroll
      for (int i = 0; i < 16; ++i) {
        A2[2 * i] = __hip_atomic_load((const uint64_t*)(srcH + i * 64),
                                      __ATOMIC_RELAXED, __HIP_MEMORY_SCOPE_AGENT);
        A2[2 * i + 1] = __hip_atomic_load((const uint64_t*)(srcH + i * 64 + 8),
                                          __ATOMIC_RELAXED, __HIP_MEMORY_SCOPE_AGENT);
      }
    }

    if (outH) {
      float4* ow = (float4*)(outH + (size_t)(t * 64 + cb) * 1024 +
                             dir * 512 + bn * 16 + cu0);
      *ow = make_float4(h2v[0], h2v[1], h2v[2], h2v[3]);
    }
    if (s == S_LEN - 1) {
      size_t fi = (size_t)cb * 1024 + dir * 512 + bn * 16 + cu0;
      *(float4*)(hn + fi) = make_float4(h2v[0], h2v[1], h2v[2], h2v[3]);
      *(float4*)(cn + fi) = make_float4(c2v[0], c2v[1], c2v[2], c2v[3]);
    }

    if (s < S_LEN - 1) {
      int tnx = dir ? (t - 1) : (t + 1);
      gvA = *(const bf16x8*)(Gd + (size_t)(tnx * 64 + cb) * 4096 +
                             bn * 128 + (lane & 3) * 32);
      gvB = *(const bf16x8*)(Gd + (size_t)(tnx * 64 + cb) * 4096 +
                             bn * 128 + (lane & 3) * 32 + 16);
      mreg = mask[tnx * 64 + cb];
    }
  }
}

// ---------- launcher ----------

extern "C" void kernel_launch(void* const* d_in, const int* in_sizes, int n_in,
                              void* d_out, int out_size, void* d_ws, size_t ws_size,
                              hipStream_t stream) {
  const float* x    = (const float*)d_in[0];
  const float* mask = (const float*)d_in[1];
  const float* Wih[4] = {(const float*)d_in[2], (const float*)d_in[6],
                         (const float*)d_in[10], (const float*)d_in[14]};
  const float* Whh[4] = {(const float*)d_in[3], (const float*)d_in[7],
                         (const float*)d_in[11], (const float*)d_in[15]};
  const float* bih[4] = {(const float*)d_in[4], (const float*)d_in[8],
                         (const float*)d_in[12], (const float*)d_in[16]};
  const float* bhh[4] = {(const float*)d_in[5], (const float*)d_in[9],
                         (const float*)d_in[13], (const float*)d_in[17]};

  char* ws = (char*)d_ws;
  __hip_bfloat16* Xbf   = (__hip_bfloat16*)(ws);                 // 32 MB
  __hip_bfloat16* Y0    = (__hip_bfloat16*)(ws + 33554432);      // 64 MB
  __hip_bfloat16* Y1    = (__hip_bfloat16*)(ws + 100663296);     // 64 MB
  __hip_bfloat16* WpIh0 = (__hip_bfloat16*)(ws + 167772160);     // 4 MB
  __hip_bfloat16* WpIh1 = (__hip_bfloat16*)(ws + 171966464);     // 8 MB
  __hip_bfloat16* WpHh  = (__hip_bfloat16*)(ws + 180355072);     // 8 MB
  float*          bsum  = (float*)(ws + 188743680);              // 32 KB
  __hip_bfloat16* Gbuf  = (__hip_bfloat16*)(ws + 188776448);     // 256 MB
  // total ws needed: ~457 MB

  float* out = (float*)d_out;
  float* hn = out + (size_t)S_LEN * BATCH * 1024;
  float* cn = hn + 2 * BATCH * 1024;

  // sentinel-fill the h-exchange buffers (0xFFFF bf16 = NaN, unreachable)
  hipMemsetAsync(Y0, 0xFF, (size_t)SB * 1024 * 2, stream);
  hipMemsetAsync(Y1, 0xFF, (size_t)SB * 1024 * 2, stream);

  // prep
  k_f32_to_bf16<<<8192, 256, 0, stream>>>(x, Xbf, SB * DDIM);
  for (int ld = 0; ld < 4; ld++) {
    int K = (ld < 2) ? 512 : 1024;
    __hip_bfloat16* dst = (ld < 2) ? (WpIh0 + (size_t)ld * 2048 * 512)
                                   : (WpIh1 + (size_t)(ld - 2) * 2048 * 1024);
    k_permW<<<(2048 * K) / 256, 256, 0, stream>>>(Wih[ld], dst, K);
    k_permW<<<(2048 * 512) / 256, 256, 0, stream>>>(Whh[ld], WpHh + (size_t)ld * 2048 * 512, 512);
    k_permB<<<8, 256, 0, stream>>>(bih[ld], bhh[ld], bsum + ld * 2048);
  }

  // layer 0
  k_gemm_in<<<dim3(256, 32), 256, 0, stream>>>(Xbf, WpIh0, bsum, Gbuf, 512);
  k_scan<<<256, 64, 0, stream>>>(Gbuf, WpHh, Y0, mask, nullptr, hn, cn);
  // layer 1
  k_gemm_in<<<dim3(256, 32), 256, 0, stream>>>(Y0, WpIh1, bsum + 2 * 2048, Gbuf, 1024);
  k_scan<<<256, 64, 0, stream>>>(Gbuf, WpHh + (size_t)2 * 2048 * 512, Y1, mask,
                                 out, hn + 2 * BATCH * 512, cn + 2 * BATCH * 512);
}